// Round 1
// baseline (149.807 us; speedup 1.0000x reference)
//
#include <hip/hip_runtime.h>

// LinearSiso: y[t] = b0*u[t] + b1*u[t-1] - a1*y[t-1] - a2*y[t-2]
// B=1024 rows, T=16384. Block-per-row chunked parallel recurrence via
// superposition: Phase A (zero-state per 64-elem chunk, 1 chunk/thread),
// serial 2x2 affine scan over 256 chunk boundary states (thread 0),
// Phase C (exact recurrence per chunk from true start state).

constexpr int T_LEN = 16384;
constexpr int LCH   = 64;    // chunk length per thread
constexpr int NCH   = 256;   // chunks per row == threads per block

__global__ __launch_bounds__(NCH) void iir_kernel(
    const float* __restrict__ bco, const float* __restrict__ aco,
    const float* __restrict__ u,   const float* __restrict__ y_init,
    const float* __restrict__ u_init, float* __restrict__ y)
{
    __shared__ float sh_e1[NCH], sh_e2[NCH];   // zero-state chunk end pairs
    __shared__ float sh_s1[NCH], sh_s2[NCH];   // true chunk start states

    const int row = blockIdx.x;
    const int tid = threadIdx.x;

    const float b0 = bco[0], b1 = bco[1];
    const float a1 = aco[0], a2 = aco[1];

    const float* __restrict__ urow = u + (size_t)row * T_LEN;
    float* __restrict__ yrow       = y + (size_t)row * T_LEN;
    const int base = tid * LCH;

    // u[base-1]: chunk boundary input (u_init[row][0] == u[-1] for chunk 0)
    const float u_prev0 = (tid == 0) ? u_init[2 * row + 0] : urow[base - 1];

    const float4* __restrict__ u4 = (const float4*)(urow + base);

    // One recurrence step: consumes UC (=u[t]), produces OUTV (=y[t]).
#define IIR_STEP(UC, OUTV)                                        \
    {                                                             \
        float x_ = fmaf(b0, (UC), b1 * up);                       \
        (OUTV) = fmaf(-a2, y2, fmaf(-a1, y1, x_));                \
        y2 = y1; y1 = (OUTV); up = (UC);                          \
    }

    // ---------------- Phase A: zero-state response per chunk ----------------
    float up = u_prev0, y1 = 0.f, y2 = 0.f;
    #pragma unroll
    for (int q = 0; q < LCH / 4; ++q) {
        float4 v = u4[q];
        float t0, t1c, t2c, t3c;
        IIR_STEP(v.x, t0);
        IIR_STEP(v.y, t1c);
        IIR_STEP(v.z, t2c);
        IIR_STEP(v.w, t3c);
        (void)t0; (void)t1c; (void)t2c; (void)t3c;
    }
    sh_e1[tid] = y1;   // y0[L-1]
    sh_e2[tid] = y2;   // y0[L-2]
    __syncthreads();

    // ---------------- Scan: compose chunk boundary states (thread 0) -------
    if (tid == 0) {
        // homogeneous response p[k]: p[-1]=1, p[-2]=0, p[k] = -a1 p[k-1] - a2 p[k-2]
        float pa = 1.f, pb = 0.f;          // p[k-1], p[k-2]
        #pragma unroll
        for (int k = 0; k <= LCH - 2; ++k) {
            float pn = fmaf(-a2, pb, -(a1 * pa));
            pb = pa; pa = pn;
        }
        const float pL2 = pa, pL3 = pb;                    // p[L-2], p[L-3]
        const float pL1 = fmaf(-a2, pL3, -(a1 * pL2));     // p[L-1]
        const float qL1 = -a2 * pL2;                       // q[L-1]
        const float qL2 = -a2 * pL3;                       // q[L-2]

        float s1 = y_init[2 * row + 0];   // y[-1]
        float s2 = y_init[2 * row + 1];   // y[-2]
        for (int c = 0; c < NCH; ++c) {
            sh_s1[c] = s1; sh_s2[c] = s2;
            float n1 = fmaf(qL1, s2, fmaf(pL1, s1, sh_e1[c]));
            float n2 = fmaf(qL2, s2, fmaf(pL2, s1, sh_e2[c]));
            s1 = n1; s2 = n2;
        }
    }
    __syncthreads();

    // ---------------- Phase C: exact recurrence from true start state ------
    up = u_prev0;
    y1 = sh_s1[tid];   // y[base-1]
    y2 = sh_s2[tid];   // y[base-2]
    float4* __restrict__ y4 = (float4*)(yrow + base);
    #pragma unroll
    for (int q = 0; q < LCH / 4; ++q) {
        float4 v = u4[q];
        float4 o;
        IIR_STEP(v.x, o.x);
        IIR_STEP(v.y, o.y);
        IIR_STEP(v.z, o.z);
        IIR_STEP(v.w, o.w);
        y4[q] = o;
    }
#undef IIR_STEP
}

extern "C" void kernel_launch(void* const* d_in, const int* in_sizes, int n_in,
                              void* d_out, int out_size, void* d_ws, size_t ws_size,
                              hipStream_t stream) {
    const float* b  = (const float*)d_in[0];
    const float* a  = (const float*)d_in[1];
    const float* u  = (const float*)d_in[2];
    const float* yi = (const float*)d_in[3];
    const float* ui = (const float*)d_in[4];
    float* yout = (float*)d_out;

    const int B = in_sizes[2] / T_LEN;   // 1024 rows
    iir_kernel<<<B, NCH, 0, stream>>>(b, a, u, yi, ui, yout);
}

// Round 2
// 136.630 us; speedup vs baseline: 1.0964x; 1.0964x over previous
//
#include <hip/hip_runtime.h>

// LinearSiso IIR, round 2: fully-coalesced global I/O via 64KB LDS row staging
// with XOR-swizzled float4 layout. Same chunked parallel recurrence as R1:
// Phase A (zero-state per 64-elem chunk), serial 2x2 affine boundary scan,
// Phase C (exact recurrence, y overwrites u in LDS), coalesced stage-out.

constexpr int T_LEN = 16384;
constexpr int LCH   = 64;    // chunk length per thread
constexpr int NCH   = 256;   // chunks per row == threads per block

// physical float4 slot in LDS for (chunk t, quarter q)
__device__ __forceinline__ int swz(int t, int q) {
    return t * 16 + (q ^ (t & 15));
}

__global__ __launch_bounds__(NCH) void iir_kernel(
    const float* __restrict__ bco, const float* __restrict__ aco,
    const float* __restrict__ u,   const float* __restrict__ y_init,
    const float* __restrict__ u_init, float* __restrict__ y)
{
    __shared__ float4 lds[T_LEN / 4];          // 64 KB row buffer (swizzled)
    __shared__ float sh_e1[NCH], sh_e2[NCH];   // zero-state chunk end pairs
    __shared__ float sh_s1[NCH], sh_s2[NCH];   // true chunk start states

    const int row = blockIdx.x;
    const int tid = threadIdx.x;

    const float b0 = bco[0], b1 = bco[1];
    const float a1 = aco[0], a2 = aco[1];

    const float4* __restrict__ u4 = (const float4*)(u + (size_t)row * T_LEN);
    float4* __restrict__ y4       = (float4*)(y + (size_t)row * T_LEN);

    // ---------------- Stage in: coalesced global -> swizzled LDS -----------
    #pragma unroll
    for (int s = 0; s < 16; ++s) {
        const int g = s * 256 + tid;           // global float4 index
        const int t = g >> 4, q = g & 15;
        lds[swz(t, q)] = u4[g];
    }
    __syncthreads();

    // u[base-1] for this thread's chunk (chunk 0: u_init[row][0] == u[-1])
    float u_prev0;
    if (tid == 0) {
        u_prev0 = u_init[2 * row + 0];
    } else {
        const float* ldsf = (const float*)lds;
        u_prev0 = ldsf[swz(tid - 1, 15) * 4 + 3];
    }

#define IIR_STEP(UC, OUTV)                                        \
    {                                                             \
        float x_ = fmaf(b0, (UC), b1 * up);                       \
        (OUTV) = fmaf(-a2, y2, fmaf(-a1, y1, x_));                \
        y2 = y1; y1 = (OUTV); up = (UC);                          \
    }

    // ---------------- Phase A: zero-state response per chunk ----------------
    float up = u_prev0, y1 = 0.f, y2 = 0.f;
    #pragma unroll
    for (int q = 0; q < 16; ++q) {
        float4 v = lds[swz(tid, q)];
        float t0, t1c, t2c, t3c;
        IIR_STEP(v.x, t0);
        IIR_STEP(v.y, t1c);
        IIR_STEP(v.z, t2c);
        IIR_STEP(v.w, t3c);
        (void)t0; (void)t1c; (void)t2c; (void)t3c;
    }
    sh_e1[tid] = y1;   // y0[L-1]
    sh_e2[tid] = y2;   // y0[L-2]
    __syncthreads();

    // ---------------- Scan: compose chunk boundary states (thread 0) -------
    if (tid == 0) {
        // homogeneous response p[k]: p[-1]=1, p[-2]=0, p[k] = -a1 p[k-1] - a2 p[k-2]
        float pa = 1.f, pb = 0.f;          // p[k-1], p[k-2]
        #pragma unroll
        for (int k = 0; k <= LCH - 2; ++k) {
            float pn = fmaf(-a2, pb, -(a1 * pa));
            pb = pa; pa = pn;
        }
        const float pL2 = pa, pL3 = pb;                    // p[L-2], p[L-3]
        const float pL1 = fmaf(-a2, pL3, -(a1 * pL2));     // p[L-1]
        const float qL1 = -a2 * pL2;                       // q[L-1]
        const float qL2 = -a2 * pL3;                       // q[L-2]

        float s1 = y_init[2 * row + 0];   // y[-1]
        float s2 = y_init[2 * row + 1];   // y[-2]
        for (int c = 0; c < NCH; ++c) {
            sh_s1[c] = s1; sh_s2[c] = s2;
            float n1 = fmaf(qL1, s2, fmaf(pL1, s1, sh_e1[c]));
            float n2 = fmaf(qL2, s2, fmaf(pL2, s1, sh_e2[c]));
            s1 = n1; s2 = n2;
        }
    }
    __syncthreads();

    // ---------------- Phase C: exact recurrence, y overwrites u in LDS -----
    up = u_prev0;
    y1 = sh_s1[tid];   // y[base-1]
    y2 = sh_s2[tid];   // y[base-2]
    #pragma unroll
    for (int q = 0; q < 16; ++q) {
        const int slot = swz(tid, q);
        float4 v = lds[slot];
        float4 o;
        IIR_STEP(v.x, o.x);
        IIR_STEP(v.y, o.y);
        IIR_STEP(v.z, o.z);
        IIR_STEP(v.w, o.w);
        lds[slot] = o;
    }
#undef IIR_STEP
    __syncthreads();

    // ---------------- Stage out: swizzled LDS -> coalesced global ----------
    #pragma unroll
    for (int s = 0; s < 16; ++s) {
        const int g = s * 256 + tid;
        const int t = g >> 4, q = g & 15;
        y4[g] = lds[swz(t, q)];
    }
}

extern "C" void kernel_launch(void* const* d_in, const int* in_sizes, int n_in,
                              void* d_out, int out_size, void* d_ws, size_t ws_size,
                              hipStream_t stream) {
    const float* b  = (const float*)d_in[0];
    const float* a  = (const float*)d_in[1];
    const float* u  = (const float*)d_in[2];
    const float* yi = (const float*)d_in[3];
    const float* ui = (const float*)d_in[4];
    float* yout = (float*)d_out;

    const int B = in_sizes[2] / T_LEN;   // 1024 rows
    iir_kernel<<<B, NCH, 0, stream>>>(b, a, u, yi, ui, yout);
}

// Round 3
// 123.365 us; speedup vs baseline: 1.2143x; 1.1075x over previous
//
#include <hip/hip_runtime.h>

// LinearSiso IIR, round 3: block = row, processed as two 8192-sample halves
// so LDS = 32KB + aux -> 4 blocks/CU, single generation (1024 blocks all
// resident). Chunked parallel recurrence per half (256 chunks x 32 samples),
// boundary-state composition via hierarchical parallel scan (intra-wave
// shfl Kogge-Stone with 2x2 matrix powers + cross-wave totals, 1 barrier).
// Coalesced global I/O through XOR-swizzled LDS; stage-out(h0) fused with
// stage-in(h1).

constexpr int T_LEN = 16384;
constexpr int HALF  = 8192;   // samples per half
constexpr int NCH   = 256;    // threads = chunks per half
constexpr int LCH   = 32;     // samples per chunk
constexpr int NQ    = 8;      // float4 quarters per chunk
constexpr int NSTG  = 8;      // stage iterations: HALF/4/NCH

// physical float4 slot for logical (chunk t, quarter q)
__device__ __forceinline__ int swz(int t, int q) {
    return t * NQ + (q ^ (t & (NQ - 1)));
}

__global__ __launch_bounds__(NCH, 4) void iir_kernel(
    const float* __restrict__ bco, const float* __restrict__ aco,
    const float* __restrict__ u,   const float* __restrict__ y_init,
    const float* __restrict__ u_init, float* __restrict__ y)
{
    __shared__ float4 lds[HALF / 4];       // 32 KB half-row buffer (swizzled)
    __shared__ float sh_wt1[4], sh_wt2[4]; // per-wave scan totals
    __shared__ float sh_carry[3];          // y[8191], y[8190], u[8191] of half0

    const int row  = blockIdx.x;
    const int tid  = threadIdx.x;
    const int lane = tid & 63;
    const int wave = tid >> 6;

    const float b0 = bco[0], b1 = bco[1];
    const float a1 = aco[0], a2 = aco[1];

    const float4* __restrict__ u4 = (const float4*)(u + (size_t)row * T_LEN);
    float4*       __restrict__ y4 = (float4*)(y + (size_t)row * T_LEN);
    const float*  ldsf = (const float*)lds;

    // ---- chunk-transition matrix M (LCH steps) and powers M^(2^k), k=0..6 ----
    // p[-1]=1, p[-2]=0, p[k] = -a1 p[k-1] - a2 p[k-2]
    float pa = 1.f, pb = 0.f;
    #pragma unroll
    for (int k = 0; k <= LCH - 2; ++k) { float pn = fmaf(-a2, pb, -(a1 * pa)); pb = pa; pa = pn; }
    const float pL2 = pa, pL3 = pb;
    const float pL1 = fmaf(-a2, pL3, -(a1 * pL2));
    float m11[7], m12[7], m21[7], m22[7];
    m11[0] = pL1; m12[0] = -a2 * pL2; m21[0] = pL2; m22[0] = -a2 * pL3;
    #pragma unroll
    for (int k = 1; k < 7; ++k) {   // square
        m11[k] = fmaf(m11[k-1], m11[k-1], m12[k-1] * m21[k-1]);
        m12[k] = fmaf(m11[k-1], m12[k-1], m12[k-1] * m22[k-1]);
        m21[k] = fmaf(m21[k-1], m11[k-1], m22[k-1] * m21[k-1]);
        m22[k] = fmaf(m21[k-1], m12[k-1], m22[k-1] * m22[k-1]);
    }
    // per-lane P = M^(lane+1) via binary decomposition (powers commute)
    float P11 = 1.f, P12 = 0.f, P21 = 0.f, P22 = 1.f;
    {
        const int e = lane + 1;
        #pragma unroll
        for (int k = 0; k < 7; ++k) {
            if ((e >> k) & 1) {
                float n11 = fmaf(m11[k], P11, m12[k] * P21);
                float n12 = fmaf(m11[k], P12, m12[k] * P22);
                float n21 = fmaf(m21[k], P11, m22[k] * P21);
                float n22 = fmaf(m21[k], P12, m22[k] * P22);
                P11 = n11; P12 = n12; P21 = n21; P22 = n22;
            }
        }
    }

    // ---- stage in half 0: coalesced global -> swizzled LDS ----
    #pragma unroll
    for (int s = 0; s < NSTG; ++s) {
        const int g = s * NCH + tid;
        lds[swz(g >> 3, g & 7)] = u4[g];
    }

#define IIR_STEP(UC, OUTV)                                        \
    {                                                             \
        float x_ = fmaf(b0, (UC), b1 * up);                       \
        (OUTV) = fmaf(-a2, y2, fmaf(-a1, y1, x_));                \
        y2 = y1; y1 = (OUTV); up = (UC);                          \
    }

    #pragma unroll 1
    for (int h = 0; h < 2; ++h) {
        __syncthreads();   // staged u visible

        // u[chunk_base - 1]
        float up0;
        if (tid == 0) up0 = (h == 0) ? u_init[2 * row] : sh_carry[2];
        else          up0 = ldsf[swz(tid - 1, 7) * 4 + 3];

        // ---- Phase A: zero-state response of own chunk ----
        float up = up0, y1 = 0.f, y2 = 0.f;
        #pragma unroll
        for (int q = 0; q < NQ; ++q) {
            float4 v = lds[swz(tid, q)];
            float t0, t1, t2, t3;
            IIR_STEP(v.x, t0); IIR_STEP(v.y, t1);
            IIR_STEP(v.z, t2); IIR_STEP(v.w, t3);
            (void)t0; (void)t1; (void)t2; (void)t3;
        }
        float v1 = y1, v2 = y2;                 // e_c
        if (tid == NCH - 1 && h == 0) sh_carry[2] = up;   // u[8191]

        // fold initial state into e_0:  e'_0 = e_0 + M s0
        float s01 = 0.f, s02 = 0.f;
        if (tid == 0) {
            s01 = (h == 0) ? y_init[2 * row]     : sh_carry[0];
            s02 = (h == 0) ? y_init[2 * row + 1] : sh_carry[1];
            v1 = fmaf(m11[0], s01, fmaf(m12[0], s02, v1));
            v2 = fmaf(m21[0], s01, fmaf(m22[0], s02, v2));
        }

        // ---- intra-wave inclusive scan: v_c += M^d v_{c-d}, d=1..32 ----
        #pragma unroll
        for (int k = 0; k < 6; ++k) {
            const int d = 1 << k;
            float t1 = __shfl_up(v1, d);
            float t2 = __shfl_up(v2, d);
            if (lane >= d) {
                v1 = fmaf(m11[k], t1, fmaf(m12[k], t2, v1));
                v2 = fmaf(m21[k], t1, fmaf(m22[k], t2, v2));
            }
        }
        if (lane == 63) { sh_wt1[wave] = v1; sh_wt2[wave] = v2; }
        __syncthreads();

        // ---- cross-wave: Q_w = sum_{v<w} M^64(w-1-v) W_v ----
        float q1 = 0.f, q2 = 0.f;
        for (int w = 0; w < wave; ++w) {
            float n1 = fmaf(m11[6], q1, fmaf(m12[6], q2, sh_wt1[w]));
            float n2 = fmaf(m21[6], q1, fmaf(m22[6], q2, sh_wt2[w]));
            q1 = n1; q2 = n2;
        }
        // global inclusive prefix for this thread
        float w1 = fmaf(P11, q1, fmaf(P12, q2, v1));
        float w2 = fmaf(P21, q1, fmaf(P22, q2, v2));
        // exclusive: start state s_c = w'_{c-1}
        float x1 = __shfl_up(w1, 1);
        float x2 = __shfl_up(w2, 1);
        if (lane == 0) { x1 = q1; x2 = q2; }
        if (tid == 0)  { x1 = s01; x2 = s02; }

        // ---- Phase C: exact recurrence, y overwrites u in place ----
        up = up0; y1 = x1; y2 = x2;
        #pragma unroll
        for (int q = 0; q < NQ; ++q) {
            const int slot = swz(tid, q);
            float4 v = lds[slot];
            float4 o;
            IIR_STEP(v.x, o.x); IIR_STEP(v.y, o.y);
            IIR_STEP(v.z, o.z); IIR_STEP(v.w, o.w);
            lds[slot] = o;
        }
        if (tid == NCH - 1) { sh_carry[0] = y1; sh_carry[1] = y2; }
        __syncthreads();   // all y in LDS

        // ---- fused stage: write y(half0) out, load u(half1) in ----
        if (h == 0) {
            #pragma unroll
            for (int s = 0; s < NSTG; ++s) {
                const int g = s * NCH + tid;
                const int slot = swz(g >> 3, g & 7);
                float4 o = lds[slot];
                y4[g] = o;
                float4 v = u4[(HALF / 4) + g];
                lds[slot] = v;
            }
        }
    }
#undef IIR_STEP

    // ---- stage out half 1 ----
    #pragma unroll
    for (int s = 0; s < NSTG; ++s) {
        const int g = s * NCH + tid;
        y4[(HALF / 4) + g] = lds[swz(g >> 3, g & 7)];
    }
}

extern "C" void kernel_launch(void* const* d_in, const int* in_sizes, int n_in,
                              void* d_out, int out_size, void* d_ws, size_t ws_size,
                              hipStream_t stream) {
    const float* b  = (const float*)d_in[0];
    const float* a  = (const float*)d_in[1];
    const float* u  = (const float*)d_in[2];
    const float* yi = (const float*)d_in[3];
    const float* ui = (const float*)d_in[4];
    float* yout = (float*)d_out;

    const int B = in_sizes[2] / T_LEN;   // 1024 rows
    iir_kernel<<<B, NCH, 0, stream>>>(b, a, u, yi, ui, yout);
}